// Round 7
// baseline (1443.955 us; speedup 1.0000x reference)
//
#include <hip/hip_runtime.h>
#include <hip/hip_fp16.h>
#include <math.h>

#define NN 100000
#define EE 1600000
#define DD 128
#define NBUCK 196          // ceil(NN / 512) buckets of 512 dst nodes
#define NBLKP 196          // partition blocks, 8192 edges each
#define EPB 8192           // edges per partition block

// ---------- bucketed CSR build (unchanged from R5) ----------
__global__ __launch_bounds__(256) void part_hist_k(const int* __restrict__ dst, int* __restrict__ bcnt) {
    __shared__ int lc[NBUCK];
    int t = threadIdx.x, blk = blockIdx.x;
    if (t < NBUCK) lc[t] = 0;
    __syncthreads();
    int e0 = blk * EPB;
    for (int i = t; i < EPB; i += 256) {
        int e = e0 + i;
        if (e < EE) atomicAdd(&lc[dst[e] >> 9], 1);
    }
    __syncthreads();
    if (t < NBUCK) bcnt[t * NBLKP + blk] = lc[t];
}

__global__ __launch_bounds__(256) void scanBB_k(const int* __restrict__ bcnt, int* __restrict__ ebase,
                                                int* __restrict__ btot) {
    __shared__ int sh[256];
    int t = threadIdx.x, b = blockIdx.x;
    int c = (t < NBLKP) ? bcnt[b * NBLKP + t] : 0;
    sh[t] = c;
    __syncthreads();
    for (int off = 1; off < 256; off <<= 1) {
        int v = (t >= off) ? sh[t - off] : 0;
        __syncthreads();
        sh[t] += v;
        __syncthreads();
    }
    if (t < NBLKP) ebase[b * NBLKP + t] = sh[t] - c;
    if (t == 255) btot[b] = sh[255];
}

__global__ __launch_bounds__(256) void scanBT_k(const int* __restrict__ btot, int* __restrict__ bstart,
                                                int* __restrict__ offsets) {
    __shared__ int sh[256];
    int t = threadIdx.x;
    int c = (t < NBUCK) ? btot[t] : 0;
    sh[t] = c;
    __syncthreads();
    for (int off = 1; off < 256; off <<= 1) {
        int v = (t >= off) ? sh[t - off] : 0;
        __syncthreads();
        sh[t] += v;
        __syncthreads();
    }
    if (t < NBUCK) bstart[t] = sh[t] - c;
    if (t == 0) { bstart[NBUCK] = EE; offsets[NN] = EE; }
}

__global__ __launch_bounds__(256) void part_k(const int* __restrict__ src, const int* __restrict__ dst,
                                              const int* __restrict__ bstart, const int* __restrict__ ebase,
                                              int2* __restrict__ ebuf) {
    __shared__ int cur[NBUCK];
    int t = threadIdx.x, blk = blockIdx.x;
    if (t < NBUCK) cur[t] = bstart[t] + ebase[t * NBLKP + blk];
    __syncthreads();
    int e0 = blk * EPB;
    for (int i = t; i < EPB; i += 256) {
        int e = e0 + i;
        if (e < EE) {
            int s = src[e], d = dst[e];
            int p = atomicAdd(&cur[d >> 9], 1);
            ebuf[p] = make_int2(s, d);
        }
    }
}

__global__ __launch_bounds__(512) void bucket_sort_k(const int2* __restrict__ ebuf,
                                                     const int* __restrict__ bstart,
                                                     int* __restrict__ offsets,
                                                     int* __restrict__ ssrc) {
    __shared__ int sh[512];
    __shared__ int cur[512];
    int t = threadIdx.x, b = blockIdx.x;
    int d0 = b << 9;
    int beg = bstart[b], end = bstart[b + 1];

    cur[t] = 0;
    __syncthreads();
    for (int e = beg + t; e < end; e += 512) atomicAdd(&cur[ebuf[e].y - d0], 1);
    __syncthreads();
    int c = cur[t];
    sh[t] = c;
    __syncthreads();
    for (int off = 1; off < 512; off <<= 1) {
        int v = (t >= off) ? sh[t - off] : 0;
        __syncthreads();
        sh[t] += v;
        __syncthreads();
    }
    int excl = sh[t] - c;
    if (d0 + t < NN) offsets[d0 + t] = beg + excl;
    cur[t] = beg + excl;
    __syncthreads();
    for (int e = beg + t; e < end; e += 512) {
        int2 ed = ebuf[e];
        int p = atomicAdd(&cur[ed.y - d0], 1);
        ssrc[p] = ed.x;
    }
}

// ---------------- GEMM: 128x128 tile, KC=32, 32 KB LDS ----------------
// MODE 0: Yf = leaky(X@W + bias, 0.01)  (fp32 row-major out)
// MODE 1: Yh = fp16(X@W) written SLICE-MAJOR [slice][node][16ch]; alpha from fp32 acc
template <int MODE>
__global__ __launch_bounds__(256, 3) void gemm_k(const float* __restrict__ X,
                                                 const float* __restrict__ W,
                                                 const float* __restrict__ bias,
                                                 const float* __restrict__ av_src,
                                                 const float* __restrict__ av_dst,
                                                 float* __restrict__ Yf,
                                                 __half* __restrict__ Yh,
                                                 float* __restrict__ alpha_src,
                                                 float* __restrict__ alpha_dst) {
    __shared__ float sX[32 * 128];
    __shared__ float sW[32 * 128];
    int t = threadIdx.x;
    int row0 = blockIdx.x * 128;
    int tm = t >> 4, tn = t & 15;

    float acc[2][2][4][4] = {};

    const float4* W4 = (const float4*)W;
    float4* sW4 = (float4*)sW;
    float4* sX4 = (float4*)sX;

    int xm = t >> 1;
    int xrow = row0 + xm;
    bool xvalid = xrow < NN;
    const float4* Xrow4 = (const float4*)(X + (size_t)xrow * DD);
    int xko = (t & 1) * 16;

    for (int kc = 0; kc < DD; kc += 32) {
        __syncthreads();
#pragma unroll
        for (int q = 0; q < 4; q++) {
            int ko = xko + q * 4;
            float4 xv = xvalid ? Xrow4[(kc + ko) >> 2] : make_float4(0.f, 0.f, 0.f, 0.f);
            sX[(ko + 0) * 128 + xm] = xv.x;
            sX[(ko + 1) * 128 + xm] = xv.y;
            sX[(ko + 2) * 128 + xm] = xv.z;
            sX[(ko + 3) * 128 + xm] = xv.w;
        }
#pragma unroll
        for (int q = 0; q < 4; q++) {
            int idx = q * 256 + t;
            sW4[idx] = W4[kc * 32 + idx];
        }
        __syncthreads();
#pragma unroll 8
        for (int k = 0; k < 32; k++) {
            float4 x0 = sX4[k * 32 + tm];
            float4 x1 = sX4[k * 32 + 16 + tm];
            float4 w0 = sW4[k * 32 + tn];
            float4 w1 = sW4[k * 32 + 16 + tn];
            float xa[2][4] = {{x0.x, x0.y, x0.z, x0.w}, {x1.x, x1.y, x1.z, x1.w}};
            float wb[2][4] = {{w0.x, w0.y, w0.z, w0.w}, {w1.x, w1.y, w1.z, w1.w}};
#pragma unroll
            for (int a = 0; a < 2; a++)
#pragma unroll
                for (int b = 0; b < 2; b++)
#pragma unroll
                    for (int i = 0; i < 4; i++)
#pragma unroll
                        for (int j = 0; j < 4; j++)
                            acc[a][b][i][j] += xa[a][i] * wb[b][j];
        }
    }

    if (MODE == 0) {
        float4 ba = *(const float4*)(bias + tn * 4);
        float4 bb = *(const float4*)(bias + 64 + tn * 4);
#pragma unroll
        for (int a = 0; a < 2; a++) {
#pragma unroll
            for (int i = 0; i < 4; i++) {
                int row = row0 + a * 64 + tm * 4 + i;
                if (row < NN) {
                    float o0[4] = {acc[a][0][i][0] + ba.x, acc[a][0][i][1] + ba.y,
                                   acc[a][0][i][2] + ba.z, acc[a][0][i][3] + ba.w};
                    float o1[4] = {acc[a][1][i][0] + bb.x, acc[a][1][i][1] + bb.y,
                                   acc[a][1][i][2] + bb.z, acc[a][1][i][3] + bb.w};
#pragma unroll
                    for (int j = 0; j < 4; j++) {
                        o0[j] = o0[j] > 0.f ? o0[j] : 0.01f * o0[j];
                        o1[j] = o1[j] > 0.f ? o1[j] : 0.01f * o1[j];
                    }
                    *(float4*)&Yf[(size_t)row * DD + tn * 4] = make_float4(o0[0], o0[1], o0[2], o0[3]);
                    *(float4*)&Yf[(size_t)row * DD + 64 + tn * 4] = make_float4(o1[0], o1[1], o1[2], o1[3]);
                }
            }
        }
    } else {
        float4 asa = *(const float4*)(av_src + tn * 4);
        float4 asb = *(const float4*)(av_src + 64 + tn * 4);
        float4 ada = *(const float4*)(av_dst + tn * 4);
        float4 adb = *(const float4*)(av_dst + 64 + tn * 4);
        __half2* T = (__half2*)Yh;
        int sl0 = tn >> 2;              // slice of channels tn*4..tn*4+3  (0..3)
        int sl1 = 4 + sl0;              // slice of channels 64+tn*4..     (4..7)
        int wi  = (tn & 3) * 2;         // half2 index within 16-ch slice row
#pragma unroll
        for (int a = 0; a < 2; a++) {
#pragma unroll
            for (int i = 0; i < 4; i++) {
                int row = row0 + a * 64 + tm * 4 + i;
                float4 o0 = make_float4(acc[a][0][i][0], acc[a][0][i][1], acc[a][0][i][2], acc[a][0][i][3]);
                float4 o1 = make_float4(acc[a][1][i][0], acc[a][1][i][1], acc[a][1][i][2], acc[a][1][i][3]);
                if (row < NN) {
                    union { __half2 h2[2]; uint2 u; } p0, p1;
                    p0.h2[0] = __floats2half2_rn(o0.x, o0.y);
                    p0.h2[1] = __floats2half2_rn(o0.z, o0.w);
                    p1.h2[0] = __floats2half2_rn(o1.x, o1.y);
                    p1.h2[1] = __floats2half2_rn(o1.z, o1.w);
                    *(uint2*)&T[(size_t)sl0 * (NN * 8) + (size_t)row * 8 + wi] = p0.u;
                    *(uint2*)&T[(size_t)sl1 * (NN * 8) + (size_t)row * 8 + wi] = p1.u;
                }
                float pa = o0.x * asa.x + o0.y * asa.y + o0.z * asa.z + o0.w * asa.w
                         + o1.x * asb.x + o1.y * asb.y + o1.z * asb.z + o1.w * asb.w;
                float pb = o0.x * ada.x + o0.y * ada.y + o0.z * ada.z + o0.w * ada.w
                         + o1.x * adb.x + o1.y * adb.y + o1.z * adb.z + o1.w * adb.w;
#pragma unroll
                for (int off = 8; off >= 1; off >>= 1) {
                    pa += __shfl_xor(pa, off);
                    pb += __shfl_xor(pb, off);
                }
                if (tn == 0 && row < NN) {
                    alpha_src[row] = pa;
                    alpha_dst[row] = pb;
                }
            }
        }
    }
}

// ---------------- Sliced aggregation ----------------
// Grid: 8 slices x 25000 node-groups; slice = blockIdx & 7 -> pins each 3.2 MB
// tmp slice into one XCD's L2 (round-robin dispatch heuristic).
// Wave = one (node, slice): 8 groups x 8 edges in flight; lane = (group g, chanpair c).
// Softmax recomputed per slice (alpha gathers L2-resident; no max pass: |e| small).
__global__ __launch_bounds__(256) void aggs_k(const __half* __restrict__ tmp,   // [slice][node][16ch]
                                              const int* __restrict__ ssrc,
                                              const int* __restrict__ offsets,
                                              const float* __restrict__ alpha_src,
                                              const float* __restrict__ alpha_dst,
                                              __half* __restrict__ o16) {       // [slice][node][16ch]
    int blk = blockIdx.x;
    int slice = blk & 7;
    int nodeg = blk >> 3;
    int wave = threadIdx.x >> 6;
    int lane = threadIdx.x & 63;
    int node = nodeg * 4 + wave;          // 25000*4 == NN exactly
    int g = lane >> 3, c = lane & 7;

    int beg = offsets[node], end = offsets[node + 1];
    float adst = alpha_dst[node];
    const __half2* T = (const __half2*)tmp + (size_t)slice * (NN * 8);

    float2 acc = make_float2(0.f, 0.f);
    float dsum = 0.f;
    for (int j0 = beg; j0 < end; j0 += 8) {
        int j = j0 + g;
        float ex = 0.f;
        int s = 0;
        if (j < end) {
            s = ssrc[j];
            float e = alpha_src[s] + adst;
            e = e > 0.f ? e : 0.2f * e;
            ex = __expf(e);
            dsum += ex;
            float2 h = __half22float2(T[(size_t)s * 8 + c]);
            acc.x += ex * h.x;
            acc.y += ex * h.y;
        }
    }
    // reduce over the 8 edge-groups (lane bits 3..5), channel position preserved
#pragma unroll
    for (int off = 8; off <= 32; off <<= 1) {
        dsum  += __shfl_xor(dsum, off);
        acc.x += __shfl_xor(acc.x, off);
        acc.y += __shfl_xor(acc.y, off);
    }
    float inv = 1.0f / (dsum + 1e-16f);
    if (g == 0) {
        ((__half2*)o16)[(size_t)slice * (NN * 8) + (size_t)node * 8 + c] =
            __floats2half2_rn(acc.x * inv, acc.y * inv);
    }
}

// ---------------- bias + LayerNorm + LeakyReLU over all 128 channels ----------------
__global__ __launch_bounds__(256) void ln_k(const __half* __restrict__ o16,
                                            const float* __restrict__ bias,
                                            const float* __restrict__ gamma,
                                            const float* __restrict__ beta,
                                            float* __restrict__ out) {
    int wid = (blockIdx.x * 256 + threadIdx.x) >> 6;
    int lane = threadIdx.x & 63;
    float2 v = __half22float2(((const __half2*)o16)[(size_t)(lane >> 3) * (NN * 8) +
                                                    (size_t)wid * 8 + (lane & 7)]);
    float ax = v.x + bias[2 * lane];
    float ay = v.y + bias[2 * lane + 1];

    float s1 = ax + ay;
#pragma unroll
    for (int off = 32; off >= 1; off >>= 1) s1 += __shfl_xor(s1, off);
    float mu = s1 * (1.0f / 128.0f);
    float dx = ax - mu, dy = ay - mu;
    float s2 = dx * dx + dy * dy;
#pragma unroll
    for (int off = 32; off >= 1; off >>= 1) s2 += __shfl_xor(s2, off);
    float rstd = rsqrtf(s2 * (1.0f / 128.0f) + 1e-5f);

    float yx = dx * rstd * gamma[2 * lane] + beta[2 * lane];
    float yy = dy * rstd * gamma[2 * lane + 1] + beta[2 * lane + 1];
    yx = yx > 0.f ? yx : 0.01f * yx;
    yy = yy > 0.f ? yy : 0.01f * yy;
    ((float2*)out)[(size_t)wid * 64 + lane] = make_float2(yx, yy);
}

extern "C" void kernel_launch(void* const* d_in, const int* in_sizes, int n_in,
                              void* d_out, int out_size, void* d_ws, size_t ws_size,
                              hipStream_t stream) {
    const float* x       = (const float*)d_in[0];
    const int*   ei      = (const int*)d_in[1];
    const float* W_in    = (const float*)d_in[2];
    const float* b_in    = (const float*)d_in[3];
    const float* Wl      = (const float*)d_in[4];
    const float* att_src = (const float*)d_in[5];
    const float* att_dst = (const float*)d_in[6];
    const float* bias_l  = (const float*)d_in[7];
    const float* gamma   = (const float*)d_in[8];
    const float* beta    = (const float*)d_in[9];
    float* out = (float*)d_out;

    char* ws = (char*)d_ws;
    __half* tmp      = (__half*)ws; ws += (size_t)NN * DD * 2;   // 25.6 MB (slice-major)
    __half* o16      = (__half*)ws; ws += (size_t)NN * DD * 2;   // 25.6 MB (slice-major)
    float* alpha_src = (float*)ws;  ws += (size_t)NN * 4;
    float* alpha_dst = (float*)ws;  ws += (size_t)NN * 4;
    int*   offsets   = (int*)ws;    ws += (size_t)(NN + 4) * 4;
    int*   ssrc      = (int*)ws;    ws += (size_t)EE * 4;        // 6.4 MB
    int2*  ebuf      = (int2*)ws;   ws += (size_t)EE * 8;        // 12.8 MB
    int*   bcnt      = (int*)ws;    ws += (size_t)NBUCK * NBLKP * 4;
    int*   ebase     = (int*)ws;    ws += (size_t)NBUCK * NBLKP * 4;
    int*   btot      = (int*)ws;    ws += (size_t)(NBUCK + 4) * 4;
    int*   bstart    = (int*)ws;    ws += (size_t)(NBUCK + 4) * 4;

    const int* esrc = ei;
    const int* edst = ei + EE;

    // bucketed CSR build (edges constant within a launch)
    part_hist_k<<<NBLKP, 256, 0, stream>>>(edst, bcnt);
    scanBB_k<<<NBUCK, 256, 0, stream>>>(bcnt, ebase, btot);
    scanBT_k<<<1, 256, 0, stream>>>(btot, bstart, offsets);
    part_k<<<NBLKP, 256, 0, stream>>>(esrc, edst, bstart, ebase, ebuf);
    bucket_sort_k<<<NBUCK, 512, 0, stream>>>(ebuf, bstart, offsets, ssrc);

    const int gemm_grid = (NN + 127) / 128;  // 782

    // input projection: h0 = leaky(x @ W_in + b_in)
    gemm_k<0><<<gemm_grid, 256, 0, stream>>>(x, W_in, b_in, nullptr, nullptr, out, nullptr, nullptr, nullptr);

    for (int i = 0; i < 4; i++) {
        gemm_k<1><<<gemm_grid, 256, 0, stream>>>(out, Wl + (size_t)i * DD * DD, nullptr,
                                                 att_src + (size_t)i * DD, att_dst + (size_t)i * DD,
                                                 nullptr, tmp, alpha_src, alpha_dst);
        aggs_k<<<(NN / 4) * 8, 256, 0, stream>>>(tmp, ssrc, offsets, alpha_src, alpha_dst, o16);
        ln_k<<<NN / 4, 256, 0, stream>>>(o16, bias_l + (size_t)i * DD, gamma + (size_t)i * DD,
                                         beta + (size_t)i * DD, out);
    }
}